// Round 2
// baseline (5197.058 us; speedup 1.0000x reference)
//
#include <hip/hip_runtime.h>

#define H 128
#define Nn 100000
#define Ee 250000
#define N5c 20000
#define N6c 30000
#define Gg 512
#define Ll 3
#define AF 9
#define AV 64
#define BF 3
#define BV 8
#define BN_EPS 1e-5f

// ---------------- elementwise / scatter kernels ----------------

__global__ void k_atom_enc(const int* __restrict__ xa, const float* __restrict__ emb,
                           float* __restrict__ x) {
    int idx = blockIdx.x * blockDim.x + threadIdx.x;
    if (idx >= Nn * H) return;
    int n = idx >> 7, h = idx & 127;
    float s = 0.f;
#pragma unroll
    for (int f = 0; f < AF; ++f) {
        int a = xa[n * AF + f];
        s += emb[(f * AV + a) * H + h];
    }
    x[idx] = s;
}

__global__ void k_cyc_init(const int* __restrict__ xc, const float* __restrict__ emb,
                           float* __restrict__ xo, int M) {
    int idx = blockIdx.x * blockDim.x + threadIdx.x;
    if (idx >= M * H) return;
    int m = idx >> 7, h = idx & 127;
    xo[idx] = emb[xc[m] * H + h];
}

__global__ void k_edge_scatter(const float* __restrict__ x, const int* __restrict__ ei,
                               const int* __restrict__ eattr, const float* __restrict__ bemb,
                               float* __restrict__ agg) {
    int idx = blockIdx.x * blockDim.x + threadIdx.x;
    if (idx >= Ee * H) return;
    int e = idx >> 7, h = idx & 127;
    int src = ei[e], dst = ei[Ee + e];
    float v = x[src * H + h];
#pragma unroll
    for (int f = 0; f < BF; ++f) {
        int a = eattr[e * BF + f];
        v += bemb[(f * BV + a) * H + h];
    }
    v = fmaxf(v, 0.f);
    atomicAdd(&agg[dst * H + h], v);
}

__global__ void k_hin(const float* __restrict__ x, const float* __restrict__ eps,
                      float* __restrict__ agg, int layer) {
    int idx = blockIdx.x * blockDim.x + threadIdx.x;
    if (idx >= Nn * H) return;
    agg[idx] = (1.f + eps[layer]) * x[idx] + agg[idx];
}

// column-wise batch stats over C columns (blockDim.x == C)
__global__ void k_bn_stats(const float* __restrict__ h, float* __restrict__ stats,
                           int M, int C, int rpb) {
    int c = threadIdx.x;
    int r0 = blockIdx.x * rpb;
    int r1 = min(r0 + rpb, M);
    float s = 0.f, sq = 0.f;
    for (int r = r0; r < r1; ++r) {
        float v = h[(size_t)r * C + c];
        s += v;
        sq += v * v;
    }
    atomicAdd(&stats[c], s);
    atomicAdd(&stats[C + c], sq);
}

__global__ void k_bn_apply(float* __restrict__ h, const float* __restrict__ stats,
                           const float* __restrict__ g, const float* __restrict__ b,
                           int M, int C) {
    int idx = blockIdx.x * blockDim.x + threadIdx.x;
    if (idx >= M * C) return;
    int c = idx & (C - 1);  // C is power of two
    float mean = stats[c] / (float)M;
    float var = stats[C + c] / (float)M - mean * mean;
    float v = (h[idx] - mean) * rsqrtf(var + BN_EPS) * g[c] + b[c];
    h[idx] = fmaxf(v, 0.f);
}

__global__ void k_scatter_add(const float* __restrict__ xc, const int* __restrict__ row,
                              float* __restrict__ sum, float* __restrict__ cnt, int M) {
    int idx = blockIdx.x * blockDim.x + threadIdx.x;
    if (idx >= M * H) return;
    int m = idx >> 7, h = idx & 127;
    int r = row[m];
    atomicAdd(&sum[r * H + h], xc[idx]);
    if (h == 0) atomicAdd(&cnt[r], 1.f);
}

__global__ void k_div_cnt(float* __restrict__ sum, const float* __restrict__ cnt) {
    int idx = blockIdx.x * blockDim.x + threadIdx.x;
    if (idx >= Nn * H) return;
    sum[idx] /= fmaxf(cnt[idx >> 7], 1.f);
}

// ---------------- generic tiled fp32 GEMM ----------------
// out[m,n] = maybe_relu( sum_k A'[m,k]*B[k,n] + bias[n] ) (+ res[row0+m,n])
// A' row source:
//   pathk>0 : cyclic-conv gather: global row g=row0+m, cycle n=g/pathk, pos p;
//             k-index kk selects neighbor (kk>>7): p-1 / p / p+1 (wrapped);
//             element A[(n*pathk+pp)*H + (kk&127)]
//   rowidx  : A[rowidx[m]*H + kk]   (K==128)
//   else    : A[m*K + kk]
#define BM 64
#define BN 64
#define BK 16

__global__ __launch_bounds__(256) void k_gemm(
    const float* __restrict__ A, const float* __restrict__ Bm,
    const float* __restrict__ bias, const float* __restrict__ res,
    float* __restrict__ out, const int* __restrict__ rowidx,
    int M, int K, int Ncol, int pathk, int relu_flag, int row0)
{
    __shared__ float As[BK][BM + 4];
    __shared__ float Bs[BK][BN];
    int t = threadIdx.x;
    int m0 = blockIdx.x * BM;
    int n0 = blockIdx.y * BN;

    int lm = t >> 2;         // 0..63  (A-tile row)
    int lkq = (t & 3) * 4;   // 0,4,8,12 (A-tile k quad)
    int lkb = t >> 4;        // 0..15  (B-tile row)
    int lnb = (t & 15) * 4;  // 0..60  (B-tile col quad)

    int tm = (t >> 4) * 4;
    int tn = (t & 15) * 4;

    float acc[4][4] = {};

    int gm = m0 + lm;
    for (int k0 = 0; k0 < K; k0 += BK) {
        float4 av = make_float4(0.f, 0.f, 0.f, 0.f);
        if (gm < M) {
            int kk = k0 + lkq;
            const float* ap;
            if (pathk) {
                int g = row0 + gm;
                int cyc = g / pathk;
                int p = g - cyc * pathk;
                int sel = kk >> 7;        // 0:p-1  1:p  2:p+1
                int pp = p + sel - 1;
                if (pp < 0) pp += pathk;
                if (pp >= pathk) pp -= pathk;
                ap = A + (size_t)(cyc * pathk + pp) * H + (kk & 127);
            } else if (rowidx) {
                ap = A + (size_t)rowidx[gm] * H + kk;
            } else {
                ap = A + (size_t)gm * K + kk;
            }
            av = *(const float4*)ap;
        }
        As[lkq + 0][lm] = av.x;
        As[lkq + 1][lm] = av.y;
        As[lkq + 2][lm] = av.z;
        As[lkq + 3][lm] = av.w;

        float4 bv = *(const float4*)(Bm + (size_t)(k0 + lkb) * Ncol + n0 + lnb);
        *(float4*)&Bs[lkb][lnb] = bv;
        __syncthreads();
#pragma unroll
        for (int kk = 0; kk < BK; ++kk) {
            float4 a = *(const float4*)&As[kk][tm];
            float4 b = *(const float4*)&Bs[kk][tn];
            float ar[4] = {a.x, a.y, a.z, a.w};
            float br[4] = {b.x, b.y, b.z, b.w};
#pragma unroll
            for (int i = 0; i < 4; ++i)
#pragma unroll
                for (int j = 0; j < 4; ++j)
                    acc[i][j] += ar[i] * br[j];
        }
        __syncthreads();
    }

#pragma unroll
    for (int i = 0; i < 4; ++i) {
        int rm = m0 + tm + i;
        if (rm < M) {
#pragma unroll
            for (int j = 0; j < 4; ++j) {
                int cn = n0 + tn + j;
                float v = acc[i][j] + bias[cn];
                if (relu_flag) v = fmaxf(v, 0.f);
                if (res) v += res[(size_t)(row0 + rm) * Ncol + cn];
                out[(size_t)rm * Ncol + cn] = v;
            }
        }
    }
}

// ---------------- BN1 stats without materializing h1 ----------------
// Computes column sum / sumsq of (hin @ gw1 + gb1) into stats[0:256]/stats[256:512]
__global__ __launch_bounds__(256) void k_gemm_stats(
    const float* __restrict__ A, const float* __restrict__ Bm,
    const float* __restrict__ bias, float* __restrict__ stats,
    int M, int K, int Ncol)
{
    __shared__ float As[BK][BM + 4];
    __shared__ float Bs[BK][BN];
    __shared__ float redS[16][BN];
    __shared__ float redQ[16][BN];
    int t = threadIdx.x;
    int m0 = blockIdx.x * BM;
    int n0 = blockIdx.y * BN;

    int lm = t >> 2;
    int lkq = (t & 3) * 4;
    int lkb = t >> 4;
    int lnb = (t & 15) * 4;
    int tm = (t >> 4) * 4;
    int tn = (t & 15) * 4;

    float acc[4][4] = {};
    int gm = m0 + lm;
    for (int k0 = 0; k0 < K; k0 += BK) {
        float4 av = make_float4(0.f, 0.f, 0.f, 0.f);
        if (gm < M) av = *(const float4*)(A + (size_t)gm * K + k0 + lkq);
        As[lkq + 0][lm] = av.x;
        As[lkq + 1][lm] = av.y;
        As[lkq + 2][lm] = av.z;
        As[lkq + 3][lm] = av.w;
        float4 bv = *(const float4*)(Bm + (size_t)(k0 + lkb) * Ncol + n0 + lnb);
        *(float4*)&Bs[lkb][lnb] = bv;
        __syncthreads();
#pragma unroll
        for (int kk = 0; kk < BK; ++kk) {
            float4 a = *(const float4*)&As[kk][tm];
            float4 b = *(const float4*)&Bs[kk][tn];
            float ar[4] = {a.x, a.y, a.z, a.w};
            float br[4] = {b.x, b.y, b.z, b.w};
#pragma unroll
            for (int i = 0; i < 4; ++i)
#pragma unroll
                for (int j = 0; j < 4; ++j)
                    acc[i][j] += ar[i] * br[j];
        }
        __syncthreads();
    }

    float s[4] = {0.f, 0.f, 0.f, 0.f}, q[4] = {0.f, 0.f, 0.f, 0.f};
#pragma unroll
    for (int i = 0; i < 4; ++i) {
        int rm = m0 + tm + i;
        if (rm < M) {
#pragma unroll
            for (int j = 0; j < 4; ++j) {
                float v = acc[i][j] + bias[n0 + tn + j];
                s[j] += v;
                q[j] += v * v;
            }
        }
    }
#pragma unroll
    for (int j = 0; j < 4; ++j) {
        redS[t >> 4][tn + j] = s[j];
        redQ[t >> 4][tn + j] = q[j];
    }
    __syncthreads();
    if (t < BN) {
        float ss = 0.f, qq = 0.f;
#pragma unroll
        for (int g = 0; g < 16; ++g) {
            ss += redS[g][t];
            qq += redQ[g][t];
        }
        atomicAdd(&stats[n0 + t], ss);
        atomicAdd(&stats[256 + n0 + t], qq);
    }
}

// ---------------- fused GINE MLP (pass B) ----------------
// xout = relu(BN1(hin @ gw1 + gb1)) @ gw2 + gb2   (pre-BN2)
#define MLP_ROWS 32

__global__ __launch_bounds__(256) void k_mlp(
    const float* __restrict__ hin, const float* __restrict__ gw1,
    const float* __restrict__ gb1, const float* __restrict__ gbn_g,
    const float* __restrict__ gbn_b, const float* __restrict__ gw2,
    const float* __restrict__ gb2, const float* __restrict__ stats,
    float* __restrict__ xout)
{
    __shared__ float Al[MLP_ROWS][132];   // hin rows
    __shared__ float Ts[MLP_ROWS][261];   // post-BN1 activations
    __shared__ float Bs[16][128];         // weight tiles (both stages)
    __shared__ float sc[256], sh[256];
    int t = threadIdx.x;
    int r0 = blockIdx.x * MLP_ROWS;

    // fold gb1 + BN1 into scale/shift
    {
        float mean = stats[t] * (1.f / (float)Nn);
        float var = stats[256 + t] * (1.f / (float)Nn) - mean * mean;
        float s = gbn_g[t] * rsqrtf(var + BN_EPS);
        sc[t] = s;
        sh[t] = (gb1[t] - mean) * s + gbn_b[t];
    }
    // stage hin rows into LDS (32x128)
#pragma unroll
    for (int j = 0; j < 4; ++j) {
        int qd = t + j * 256;            // 0..1023 float4s
        int row = qd >> 5, c4 = (qd & 31) * 4;
        *(float4*)&Al[row][c4] = *(const float4*)&hin[(size_t)(r0 + row) * H + c4];
    }

    int tm = (t >> 4) * 2;   // 2 rows / thread
    int tn = (t & 15) * 4;   // 4 cols / thread (within 64-col panel)

    // ---- stage 1: T = relu(BN(hin @ gw1 + gb1)), 4 panels of 64 cols ----
    for (int nb = 0; nb < 4; ++nb) {
        float acc[2][4] = {};
        for (int k0 = 0; k0 < 128; k0 += 16) {
            __syncthreads();
            {
                int row = t >> 4, c4 = (t & 15) * 4;
                *(float4*)&Bs[row][c4] =
                    *(const float4*)&gw1[(size_t)(k0 + row) * 256 + nb * 64 + c4];
            }
            __syncthreads();
#pragma unroll
            for (int kk = 0; kk < 16; ++kk) {
                float a0 = Al[tm][k0 + kk];
                float a1 = Al[tm + 1][k0 + kk];
                float4 b = *(float4*)&Bs[kk][tn];
                acc[0][0] += a0 * b.x; acc[0][1] += a0 * b.y;
                acc[0][2] += a0 * b.z; acc[0][3] += a0 * b.w;
                acc[1][0] += a1 * b.x; acc[1][1] += a1 * b.y;
                acc[1][2] += a1 * b.z; acc[1][3] += a1 * b.w;
            }
        }
#pragma unroll
        for (int i = 0; i < 2; ++i)
#pragma unroll
            for (int j = 0; j < 4; ++j) {
                int c = nb * 64 + tn + j;
                Ts[tm + i][c] = fmaxf(acc[i][j] * sc[c] + sh[c], 0.f);
            }
    }

    // ---- stage 2: xout = T @ gw2 + gb2 ----
    int tm2 = (t >> 4) * 2;
    int tn2 = (t & 15) * 8;
    float acc2[2][8] = {};
    for (int k0 = 0; k0 < 256; k0 += 16) {
        __syncthreads();
#pragma unroll
        for (int j = 0; j < 2; ++j) {
            int qd = t + j * 256;        // 0..511 float4s
            int row = qd >> 5, c4 = (qd & 31) * 4;
            *(float4*)&Bs[row][c4] = *(const float4*)&gw2[(size_t)(k0 + row) * H + c4];
        }
        __syncthreads();
#pragma unroll
        for (int kk = 0; kk < 16; ++kk) {
            float a0 = Ts[tm2][k0 + kk];
            float a1 = Ts[tm2 + 1][k0 + kk];
            float4 b0 = *(float4*)&Bs[kk][tn2];
            float4 b1 = *(float4*)&Bs[kk][tn2 + 4];
            float br[8] = {b0.x, b0.y, b0.z, b0.w, b1.x, b1.y, b1.z, b1.w};
#pragma unroll
            for (int j = 0; j < 8; ++j) {
                acc2[0][j] += a0 * br[j];
                acc2[1][j] += a1 * br[j];
            }
        }
    }
#pragma unroll
    for (int i = 0; i < 2; ++i)
#pragma unroll
        for (int j = 0; j < 8; ++j)
            xout[(size_t)(r0 + tm2 + i) * H + tn2 + j] = acc2[i][j] + gb2[tn2 + j];
}

// ---------------- readout ----------------

__global__ void k_seg_batch(const float* __restrict__ x, const int* __restrict__ batch,
                            float* __restrict__ xgsum, float* __restrict__ gcnt) {
    int h = threadIdx.x;  // 128 threads
    int r0 = blockIdx.x * 256;
    if (r0 >= Nn) return;
    int r1 = min(r0 + 256, Nn);
    int cur = batch[r0];
    float acc = 0.f, c = 0.f;
    for (int r = r0; r < r1; ++r) {
        int b = batch[r];
        if (b != cur) {
            atomicAdd(&xgsum[cur * H + h], acc);
            if (h == 0) atomicAdd(&gcnt[cur], c);
            acc = 0.f;
            c = 0.f;
            cur = b;
        }
        acc += x[r * H + h];
        c += 1.f;
    }
    atomicAdd(&xgsum[cur * H + h], acc);
    if (h == 0) atomicAdd(&gcnt[cur], c);
}

__global__ void k_head(const float* __restrict__ xgsum, const float* __restrict__ gcnt,
                       const float* __restrict__ alw, const float* __restrict__ alb,
                       const float* __restrict__ lw, const float* __restrict__ lb,
                       float* __restrict__ out) {
    __shared__ float mean[H];
    __shared__ float red[H];
    int g = blockIdx.x, j = threadIdx.x;
    mean[j] = xgsum[g * H + j] / fmaxf(gcnt[g], 1.f);
    __syncthreads();
    float acc = alb[j];
    for (int k = 0; k < H; ++k) acc += mean[k] * alw[k * H + j];
    acc = fmaxf(acc, 0.f) * lw[j];
    red[j] = acc;
    __syncthreads();
    for (int s = 64; s > 0; s >>= 1) {
        if (j < s) red[j] += red[j + s];
        __syncthreads();
    }
    if (j == 0) out[g] = red[0] + lb[0];
}

// ---------------- host ----------------

extern "C" void kernel_launch(void* const* d_in, const int* in_sizes, int n_in,
                              void* d_out, int out_size, void* d_ws, size_t ws_size,
                              hipStream_t stream) {
    const int* x_atom = (const int*)d_in[0];
    const int* ei = (const int*)d_in[1];
    const int* eattr = (const int*)d_in[2];
    const int* batch = (const int*)d_in[3];
    const int* xc5 = (const int*)d_in[4];
    const int* xc6 = (const int*)d_in[5];
    const int* a2c5_row = (const int*)d_in[6];
    const int* a2c6_row = (const int*)d_in[8];
    const float* atom_emb = (const float*)d_in[10];
    const float* bond_emb = (const float*)d_in[11];
    const float* cyc5 = (const float*)d_in[12];
    const float* cyc6 = (const float*)d_in[13];
    const float* eps = (const float*)d_in[14];
    const float* gw1 = (const float*)d_in[15];
    const float* gb1 = (const float*)d_in[16];
    const float* gbn_g = (const float*)d_in[17];
    const float* gbn_b = (const float*)d_in[18];
    const float* gw2 = (const float*)d_in[19];
    const float* gb2 = (const float*)d_in[20];
    const float* bn_g = (const float*)d_in[21];
    const float* bn_b = (const float*)d_in[22];
    const float* a2c5_w = (const float*)d_in[23];
    const float* a2c5_b = (const float*)d_in[24];
    const float* a2c6_w = (const float*)d_in[25];
    const float* a2c6_b = (const float*)d_in[26];
    const float* c2a5_w = (const float*)d_in[27];
    const float* c2a5_b = (const float*)d_in[28];
    const float* c2a6_w = (const float*)d_in[29];
    const float* c2a6_b = (const float*)d_in[30];
    const float* p5_w = (const float*)d_in[31];
    const float* p5_b = (const float*)d_in[32];
    const float* p6_w = (const float*)d_in[33];
    const float* p6_b = (const float*)d_in[34];
    const float* alw = (const float*)d_in[35];
    const float* alb = (const float*)d_in[36];
    const float* lw = (const float*)d_in[37];
    const float* lb = (const float*)d_in[38];
    float* out = (float*)d_out;

    float* w = (float*)d_ws;
    size_t o = 0;
    auto alloc = [&](size_t nf) {
        float* p = w + o;
        o += (nf + 63) & ~(size_t)63;
        return p;
    };
    float* x = alloc((size_t)Nn * H);         // 12.8M
    float* x5 = alloc((size_t)N5c * 5 * H);   // 12.8M
    float* x6 = alloc((size_t)N6c * 6 * H);   // 23.04M
    float* agg = alloc((size_t)Nn * H);       // 12.8M (agg / path-tmp / scatter-sum)
    float* cnt = alloc(Nn);
    float* stats = alloc(512);
    float* xgsum = alloc((size_t)Gg * H);
    float* gcnt = alloc(Gg);
    // total ~61.6M floats ~247 MB

    const int TPB = 256;
    auto cdiv = [](int a, int b) { return (a + b - 1) / b; };

    k_atom_enc<<<cdiv(Nn * H, TPB), TPB, 0, stream>>>(x_atom, atom_emb, x);
    k_cyc_init<<<cdiv(N5c * 5 * H, TPB), TPB, 0, stream>>>(xc5, cyc5, x5, N5c * 5);
    k_cyc_init<<<cdiv(N6c * 6 * H, TPB), TPB, 0, stream>>>(xc6, cyc6, x6, N6c * 6);

    for (int i = 0; i < Ll; ++i) {
        // GINE aggregation -> agg (= hin)
        hipMemsetAsync(agg, 0, (size_t)Nn * H * 4, stream);
        k_edge_scatter<<<cdiv(Ee * H, TPB), TPB, 0, stream>>>(
            x, ei, eattr, bond_emb + (size_t)i * BF * BV * H, agg);
        k_hin<<<cdiv(Nn * H, TPB), TPB, 0, stream>>>(x, eps, agg, i);

        // BN1 stats (pass A, h1 never materialized)
        hipMemsetAsync(stats, 0, 512 * 4, stream);
        dim3 gs(cdiv(Nn, BM), 4);
        k_gemm_stats<<<gs, 256, 0, stream>>>(agg, gw1 + (size_t)i * H * 2 * H,
                                             gb1 + (size_t)i * 2 * H, stats,
                                             Nn, H, 2 * H);
        // fused MLP (pass B) -> x (pre-BN2)
        k_mlp<<<Nn / MLP_ROWS, 256, 0, stream>>>(
            agg, gw1 + (size_t)i * H * 2 * H, gb1 + (size_t)i * 2 * H,
            gbn_g + (size_t)i * 2 * H, gbn_b + (size_t)i * 2 * H,
            gw2 + (size_t)i * 2 * H * H, gb2 + (size_t)i * H, stats, x);

        // BN2 + relu on x
        hipMemsetAsync(stats, 0, 512 * 4, stream);
        k_bn_stats<<<cdiv(Nn, 64), H, 0, stream>>>(x, stats, Nn, H, 64);
        k_bn_apply<<<cdiv(Nn * H, TPB), TPB, 0, stream>>>(
            x, stats, bn_g + (size_t)i * H, bn_b + (size_t)i * H, Nn, H);

        // atoms -> cycles (gather GEMM, in-place residual on x5/x6)
        dim3 g5(cdiv(N5c * 5, BM), H / BN);
        k_gemm<<<g5, 256, 0, stream>>>(x, a2c5_w + (size_t)i * H * H,
                                       a2c5_b + (size_t)i * H, x5, x5, a2c5_row,
                                       N5c * 5, H, H, 0, 1, 0);
        dim3 g6(cdiv(N6c * 6, BM), H / BN);
        k_gemm<<<g6, 256, 0, stream>>>(x, a2c6_w + (size_t)i * H * H,
                                       a2c6_b + (size_t)i * H, x6, x6, a2c6_row,
                                       N6c * 6, H, H, 0, 1, 0);

        // path blocks: out -> agg (tmp), then copy back. x6 in 2 chunks.
        k_gemm<<<g5, 256, 0, stream>>>(x5, p5_w + (size_t)i * 3 * H * H,
                                       p5_b + (size_t)i * H, x5, agg, nullptr,
                                       N5c * 5, 3 * H, H, 5, 1, 0);
        hipMemcpyAsync(x5, agg, (size_t)N5c * 5 * H * 4, hipMemcpyDeviceToDevice, stream);
        const int C6 = (N6c / 2) * 6;  // 90000 rows per chunk
        for (int ch = 0; ch < 2; ++ch) {
            dim3 gc(cdiv(C6, BM), H / BN);
            k_gemm<<<gc, 256, 0, stream>>>(x6, p6_w + (size_t)i * 3 * H * H,
                                           p6_b + (size_t)i * H, x6, agg, nullptr,
                                           C6, 3 * H, H, 6, 1, ch * C6);
            hipMemcpyAsync(x6 + (size_t)ch * C6 * H, agg, (size_t)C6 * H * 4,
                           hipMemcpyDeviceToDevice, stream);
        }

        // cycles -> atoms (scatter-mean -> agg, then GEMM residual into x)
        dim3 ga(cdiv(Nn, BM), H / BN);
        hipMemsetAsync(agg, 0, (size_t)Nn * H * 4, stream);
        hipMemsetAsync(cnt, 0, (size_t)Nn * 4, stream);
        k_scatter_add<<<cdiv(N5c * 5 * H, TPB), TPB, 0, stream>>>(x5, a2c5_row, agg, cnt, N5c * 5);
        k_div_cnt<<<cdiv(Nn * H, TPB), TPB, 0, stream>>>(agg, cnt);
        k_gemm<<<ga, 256, 0, stream>>>(agg, c2a5_w + (size_t)i * H * H,
                                       c2a5_b + (size_t)i * H, x, x, nullptr,
                                       Nn, H, H, 0, 1, 0);
        hipMemsetAsync(agg, 0, (size_t)Nn * H * 4, stream);
        hipMemsetAsync(cnt, 0, (size_t)Nn * 4, stream);
        k_scatter_add<<<cdiv(N6c * 6 * H, TPB), TPB, 0, stream>>>(x6, a2c6_row, agg, cnt, N6c * 6);
        k_div_cnt<<<cdiv(Nn * H, TPB), TPB, 0, stream>>>(agg, cnt);
        k_gemm<<<ga, 256, 0, stream>>>(agg, c2a6_w + (size_t)i * H * H,
                                       c2a6_b + (size_t)i * H, x, x, nullptr,
                                       Nn, H, H, 0, 1, 0);
    }

    // readout
    hipMemsetAsync(xgsum, 0, (size_t)Gg * H * 4, stream);
    hipMemsetAsync(gcnt, 0, (size_t)Gg * 4, stream);
    k_seg_batch<<<cdiv(Nn, 256), H, 0, stream>>>(x, batch, xgsum, gcnt);
    k_head<<<Gg, H, 0, stream>>>(xgsum, gcnt, alw, alb, lw, lb, out);
}

// Round 4
// 3699.038 us; speedup vs baseline: 1.4050x; 1.4050x over previous
//
#include <hip/hip_runtime.h>

#define H 128
#define Nn 100000
#define Ee 250000
#define N5c 20000
#define N6c 30000
#define Gg 512
#define Ll 3
#define AF 9
#define AV 64
#define BF 3
#define BV 8
#define BN_EPS 1e-5f

typedef __bf16 v8bf __attribute__((ext_vector_type(8)));
typedef float v4f __attribute__((ext_vector_type(4)));

struct bfpair { __bf16 h, l; };
__device__ inline bfpair split2(float v) {
    bfpair r;
    r.h = (__bf16)v;
    r.l = (__bf16)(v - (float)r.h);
    return r;
}

// ---------------- elementwise / scatter kernels ----------------

__global__ void k_atom_enc(const int* __restrict__ xa, const float* __restrict__ emb,
                           float* __restrict__ x) {
    int idx = blockIdx.x * blockDim.x + threadIdx.x;
    if (idx >= Nn * H) return;
    int n = idx >> 7, h = idx & 127;
    float s = 0.f;
#pragma unroll
    for (int f = 0; f < AF; ++f) {
        int a = xa[n * AF + f];
        s += emb[(f * AV + a) * H + h];
    }
    x[idx] = s;
}

__global__ void k_cyc_init(const int* __restrict__ xc, const float* __restrict__ emb,
                           float* __restrict__ xo, int M) {
    int idx = blockIdx.x * blockDim.x + threadIdx.x;
    if (idx >= M * H) return;
    int m = idx >> 7, h = idx & 127;
    xo[idx] = emb[xc[m] * H + h];
}

__global__ void k_edge_scatter(const float* __restrict__ x, const int* __restrict__ ei,
                               const int* __restrict__ eattr, const float* __restrict__ bemb,
                               float* __restrict__ agg) {
    int idx = blockIdx.x * blockDim.x + threadIdx.x;
    if (idx >= Ee * H) return;
    int e = idx >> 7, h = idx & 127;
    int src = ei[e], dst = ei[Ee + e];
    float v = x[src * H + h];
#pragma unroll
    for (int f = 0; f < BF; ++f) {
        int a = eattr[e * BF + f];
        v += bemb[(f * BV + a) * H + h];
    }
    v = fmaxf(v, 0.f);
    atomicAdd(&agg[dst * H + h], v);
}

__global__ void k_hin(const float* __restrict__ x, const float* __restrict__ eps,
                      float* __restrict__ agg, int layer) {
    int idx = blockIdx.x * blockDim.x + threadIdx.x;
    if (idx >= Nn * H) return;
    agg[idx] = (1.f + eps[layer]) * x[idx] + agg[idx];
}

__global__ void k_bn_stats(const float* __restrict__ h, float* __restrict__ stats,
                           int M, int C, int rpb) {
    int c = threadIdx.x;
    int r0 = blockIdx.x * rpb;
    int r1 = min(r0 + rpb, M);
    float s = 0.f, sq = 0.f;
    for (int r = r0; r < r1; ++r) {
        float v = h[(size_t)r * C + c];
        s += v;
        sq += v * v;
    }
    atomicAdd(&stats[c], s);
    atomicAdd(&stats[C + c], sq);
}

__global__ void k_bn_apply(float* __restrict__ h, const float* __restrict__ stats,
                           const float* __restrict__ g, const float* __restrict__ b,
                           int M, int C) {
    int idx = blockIdx.x * blockDim.x + threadIdx.x;
    if (idx >= M * C) return;
    int c = idx & (C - 1);
    float mean = stats[c] / (float)M;
    float var = stats[C + c] / (float)M - mean * mean;
    float v = (h[idx] - mean) * rsqrtf(var + BN_EPS) * g[c] + b[c];
    h[idx] = fmaxf(v, 0.f);
}

__global__ void k_scatter_add(const float* __restrict__ xc, const int* __restrict__ row,
                              float* __restrict__ sum, float* __restrict__ cnt, int M) {
    int idx = blockIdx.x * blockDim.x + threadIdx.x;
    if (idx >= M * H) return;
    int m = idx >> 7, h = idx & 127;
    int r = row[m];
    atomicAdd(&sum[r * H + h], xc[idx]);
    if (h == 0) atomicAdd(&cnt[r], 1.f);
}

__global__ void k_div_cnt(float* __restrict__ sum, const float* __restrict__ cnt) {
    int idx = blockIdx.x * blockDim.x + threadIdx.x;
    if (idx >= Nn * H) return;
    sum[idx] /= fmaxf(cnt[idx >> 7], 1.f);
}

// ---------------- generic MFMA GEMM (bf16x3 split precision) ----------------
// out[m,n] = maybe_relu( sum_k A'[m,k]*B[k,n] + bias[n] ) (+ res[row0+m,n])
// epi==1: accumulate column sum/sumsq of (acc+bias) into stats[n], stats[Ncol+n]
// A' modes: pathk>0 cyclic-conv gather on global row (row0+m); rowidx gather (K=128);
//           else direct A[m*K + k].
// Tile: BM=128, BN=128 (grid.y panels for N>128), BK=32, 256 threads = 4 waves.

__global__ __launch_bounds__(256) void k_mgemm(
    const float* __restrict__ A, const float* __restrict__ Bm,
    const float* __restrict__ bias, const float* __restrict__ res,
    float* __restrict__ out, const int* __restrict__ rowidx,
    float* __restrict__ stats,
    int M, int K, int Ncol, int pathk, int relu_flag, int row0, int epi)
{
    __shared__ __bf16 Ah[128 * 40], Al[128 * 40];
    __shared__ __bf16 Bh[128 * 40], Bl[128 * 40];
    __shared__ float sS[128], sQ[128];

    int t = threadIdx.x;
    int m0 = blockIdx.x * 128;
    int n0 = blockIdx.y * 128;
    int lane = t & 63;
    int q = lane >> 4;       // 0..3
    int lr = lane & 15;
    int wrow = (t >> 6) * 32;  // wave row base

    v4f acc[2][8] = {};

    // staging roles
    int ar = t >> 1;               // A row 0..127
    int akq = (t & 1) * 16;        // A k sub-block 0/16
    int bn = t & 127;              // B col 0..127
    int bkb = (t >> 7) * 16;       // B k sub-block 0/16

    for (int k0 = 0; k0 < K; k0 += 32) {
        // ---- stage A (fp32 -> hi/lo bf16) ----
        {
            float va[16];
            int gm = m0 + ar;
            if (gm < M) {
                int kk = k0 + akq;
                const float* ap;
                if (pathk) {
                    int g = row0 + gm;
                    int cyc = g / pathk;
                    int p = g - cyc * pathk;
                    int sel = kk >> 7;
                    int pp = p + sel - 1;
                    if (pp < 0) pp += pathk;
                    if (pp >= pathk) pp -= pathk;
                    ap = A + (size_t)(cyc * pathk + pp) * H + (kk & 127);
                } else if (rowidx) {
                    ap = A + (size_t)rowidx[gm] * H + kk;
                } else {
                    ap = A + (size_t)gm * K + kk;
                }
#pragma unroll
                for (int i = 0; i < 4; ++i) {
                    float4 f = *(const float4*)(ap + i * 4);
                    va[i * 4 + 0] = f.x; va[i * 4 + 1] = f.y;
                    va[i * 4 + 2] = f.z; va[i * 4 + 3] = f.w;
                }
            } else {
#pragma unroll
                for (int i = 0; i < 16; ++i) va[i] = 0.f;
            }
            v8bf h0, h1, l0, l1;
#pragma unroll
            for (int i = 0; i < 8; ++i) {
                bfpair p0 = split2(va[i]);
                bfpair p1 = split2(va[8 + i]);
                h0[i] = p0.h; l0[i] = p0.l;
                h1[i] = p1.h; l1[i] = p1.l;
            }
            *(v8bf*)&Ah[ar * 40 + akq] = h0;
            *(v8bf*)&Ah[ar * 40 + akq + 8] = h1;
            *(v8bf*)&Al[ar * 40 + akq] = l0;
            *(v8bf*)&Al[ar * 40 + akq + 8] = l1;
        }
        // ---- stage B (K x N row-major -> LDS [n][k], hi/lo) ----
        {
            v8bf h0, h1, l0, l1;
#pragma unroll
            for (int j = 0; j < 8; ++j) {
                bfpair p0 = split2(Bm[(size_t)(k0 + bkb + j) * Ncol + n0 + bn]);
                bfpair p1 = split2(Bm[(size_t)(k0 + bkb + 8 + j) * Ncol + n0 + bn]);
                h0[j] = p0.h; l0[j] = p0.l;
                h1[j] = p1.h; l1[j] = p1.l;
            }
            *(v8bf*)&Bh[bn * 40 + bkb] = h0;
            *(v8bf*)&Bh[bn * 40 + bkb + 8] = h1;
            *(v8bf*)&Bl[bn * 40 + bkb] = l0;
            *(v8bf*)&Bl[bn * 40 + bkb + 8] = l1;
        }
        __syncthreads();

        v8bf ah[2], al2[2], bh[8], bl2[8];
#pragma unroll
        for (int mt = 0; mt < 2; ++mt) {
            ah[mt] = *(v8bf*)&Ah[(wrow + mt * 16 + lr) * 40 + q * 8];
            al2[mt] = *(v8bf*)&Al[(wrow + mt * 16 + lr) * 40 + q * 8];
        }
#pragma unroll
        for (int nt = 0; nt < 8; ++nt) {
            bh[nt] = *(v8bf*)&Bh[(nt * 16 + lr) * 40 + q * 8];
            bl2[nt] = *(v8bf*)&Bl[(nt * 16 + lr) * 40 + q * 8];
        }
#pragma unroll
        for (int mt = 0; mt < 2; ++mt)
#pragma unroll
            for (int nt = 0; nt < 8; ++nt) {
                v4f a = acc[mt][nt];
                a = __builtin_amdgcn_mfma_f32_16x16x32_bf16(al2[mt], bh[nt], a, 0, 0, 0);
                a = __builtin_amdgcn_mfma_f32_16x16x32_bf16(ah[mt], bl2[nt], a, 0, 0, 0);
                a = __builtin_amdgcn_mfma_f32_16x16x32_bf16(ah[mt], bh[nt], a, 0, 0, 0);
                acc[mt][nt] = a;
            }
        __syncthreads();
    }

    if (epi == 0) {
        float bcol[8];
#pragma unroll
        for (int nt = 0; nt < 8; ++nt) bcol[nt] = bias[n0 + nt * 16 + lr];
#pragma unroll
        for (int mt = 0; mt < 2; ++mt)
#pragma unroll
            for (int reg = 0; reg < 4; ++reg) {
                int rm = m0 + wrow + mt * 16 + q * 4 + reg;
                if (rm < M) {
#pragma unroll
                    for (int nt = 0; nt < 8; ++nt) {
                        int cn = n0 + nt * 16 + lr;
                        float v = acc[mt][nt][reg] + bcol[nt];
                        if (relu_flag) v = fmaxf(v, 0.f);
                        if (res) v += res[(size_t)(row0 + rm) * Ncol + cn];
                        out[(size_t)rm * Ncol + cn] = v;
                    }
                }
            }
    } else {
        if (t < 128) { sS[t] = 0.f; sQ[t] = 0.f; }
        __syncthreads();
        float bcol[8];
#pragma unroll
        for (int nt = 0; nt < 8; ++nt) bcol[nt] = bias[n0 + nt * 16 + lr];
#pragma unroll
        for (int nt = 0; nt < 8; ++nt) {
            float s = 0.f, q2 = 0.f;
#pragma unroll
            for (int mt = 0; mt < 2; ++mt)
#pragma unroll
                for (int reg = 0; reg < 4; ++reg) {
                    int rm = m0 + wrow + mt * 16 + q * 4 + reg;
                    if (rm < M) {
                        float v = acc[mt][nt][reg] + bcol[nt];
                        s += v;
                        q2 += v * v;
                    }
                }
            atomicAdd(&sS[nt * 16 + lr], s);
            atomicAdd(&sQ[nt * 16 + lr], q2);
        }
        __syncthreads();
        if (t < 128) {
            atomicAdd(&stats[n0 + t], sS[t]);
            atomicAdd(&stats[Ncol + n0 + t], sQ[t]);
        }
    }
}

// ---------------- fused GINE MLP via MFMA ----------------

__global__ __launch_bounds__(256) void k_mlp_mfma(
    const float* __restrict__ hin, const float* __restrict__ gw1,
    const float* __restrict__ gb1, const float* __restrict__ gbn_g,
    const float* __restrict__ gbn_b, const float* __restrict__ gw2,
    const float* __restrict__ gb2, const float* __restrict__ stats,
    float* __restrict__ xout)
{
    __shared__ __bf16 Ah[32 * 136], Al[32 * 136];   // hin tile 32 x 128
    __shared__ __bf16 Bh[128 * 40], Bl[128 * 40];   // weight slab 32k x 128n
    __shared__ __bf16 Th[32 * 264], Tl[32 * 264];   // T tile 32 x 256
    __shared__ float sc[256], sh[256];

    int t = threadIdx.x;
    int r0 = blockIdx.x * 32;
    int lane = t & 63;
    int q = lane >> 4;
    int lr = lane & 15;
    int w = t >> 6;  // wave 0..3

    // fold BN1
    {
        float mean = stats[t] * (1.f / (float)Nn);
        float var = stats[256 + t] * (1.f / (float)Nn) - mean * mean;
        float s = gbn_g[t] * rsqrtf(var + BN_EPS);
        sc[t] = s;
        sh[t] = (gb1[t] - mean) * s + gbn_b[t];
    }
    // stage hin tile (32 x 128) -> Ah/Al
    {
        int r = t >> 3;
        int kq = (t & 7) * 16;
        const float* ap = hin + (size_t)(r0 + r) * H + kq;
        v8bf h0, h1, l0, l1;
#pragma unroll
        for (int i = 0; i < 8; ++i) {
            bfpair p0 = split2(ap[i]);
            bfpair p1 = split2(ap[8 + i]);
            h0[i] = p0.h; l0[i] = p0.l;
            h1[i] = p1.h; l1[i] = p1.l;
        }
        *(v8bf*)&Ah[r * 136 + kq] = h0;
        *(v8bf*)&Ah[r * 136 + kq + 8] = h1;
        *(v8bf*)&Al[r * 136 + kq] = l0;
        *(v8bf*)&Al[r * 136 + kq + 8] = l1;
    }

    int bn = t & 127;
    int bkb = (t >> 7) * 16;

    // ---- stage 1: two 128-col panels of gw1 ----
    for (int p = 0; p < 2; ++p) {
        v4f acc[2][2] = {};
        for (int k0 = 0; k0 < 128; k0 += 32) {
            {
                v8bf h0, h1, l0, l1;
#pragma unroll
                for (int j = 0; j < 8; ++j) {
                    bfpair p0 = split2(gw1[(size_t)(k0 + bkb + j) * 256 + p * 128 + bn]);
                    bfpair p1 = split2(gw1[(size_t)(k0 + bkb + 8 + j) * 256 + p * 128 + bn]);
                    h0[j] = p0.h; l0[j] = p0.l;
                    h1[j] = p1.h; l1[j] = p1.l;
                }
                *(v8bf*)&Bh[bn * 40 + bkb] = h0;
                *(v8bf*)&Bh[bn * 40 + bkb + 8] = h1;
                *(v8bf*)&Bl[bn * 40 + bkb] = l0;
                *(v8bf*)&Bl[bn * 40 + bkb + 8] = l1;
            }
            __syncthreads();
            v8bf ah[2], al2[2], bh[2], bl2[2];
#pragma unroll
            for (int mt = 0; mt < 2; ++mt) {
                ah[mt] = *(v8bf*)&Ah[(mt * 16 + lr) * 136 + k0 + q * 8];
                al2[mt] = *(v8bf*)&Al[(mt * 16 + lr) * 136 + k0 + q * 8];
            }
#pragma unroll
            for (int nt = 0; nt < 2; ++nt) {
                bh[nt] = *(v8bf*)&Bh[(w * 32 + nt * 16 + lr) * 40 + q * 8];
                bl2[nt] = *(v8bf*)&Bl[(w * 32 + nt * 16 + lr) * 40 + q * 8];
            }
#pragma unroll
            for (int mt = 0; mt < 2; ++mt)
#pragma unroll
                for (int nt = 0; nt < 2; ++nt) {
                    v4f a = acc[mt][nt];
                    a = __builtin_amdgcn_mfma_f32_16x16x32_bf16(al2[mt], bh[nt], a, 0, 0, 0);
                    a = __builtin_amdgcn_mfma_f32_16x16x32_bf16(ah[mt], bl2[nt], a, 0, 0, 0);
                    a = __builtin_amdgcn_mfma_f32_16x16x32_bf16(ah[mt], bh[nt], a, 0, 0, 0);
                    acc[mt][nt] = a;
                }
            __syncthreads();
        }
#pragma unroll
        for (int mt = 0; mt < 2; ++mt)
#pragma unroll
            for (int nt = 0; nt < 2; ++nt)
#pragma unroll
                for (int reg = 0; reg < 4; ++reg) {
                    int row = mt * 16 + q * 4 + reg;
                    int col = p * 128 + w * 32 + nt * 16 + lr;
                    float v = fmaxf(acc[mt][nt][reg] * sc[col] + sh[col], 0.f);
                    bfpair pr = split2(v);
                    Th[row * 264 + col] = pr.h;
                    Tl[row * 264 + col] = pr.l;
                }
    }
    __syncthreads();

    // ---- stage 2: x = T @ gw2 + gb2 ----
    v4f acc2[2][2] = {};
    for (int k0 = 0; k0 < 256; k0 += 32) {
        {
            v8bf h0, h1, l0, l1;
#pragma unroll
            for (int j = 0; j < 8; ++j) {
                bfpair p0 = split2(gw2[(size_t)(k0 + bkb + j) * H + bn]);
                bfpair p1 = split2(gw2[(size_t)(k0 + bkb + 8 + j) * H + bn]);
                h0[j] = p0.h; l0[j] = p0.l;
                h1[j] = p1.h; l1[j] = p1.l;
            }
            *(v8bf*)&Bh[bn * 40 + bkb] = h0;
            *(v8bf*)&Bh[bn * 40 + bkb + 8] = h1;
            *(v8bf*)&Bl[bn * 40 + bkb] = l0;
            *(v8bf*)&Bl[bn * 40 + bkb + 8] = l1;
        }
        __syncthreads();
        v8bf ah[2], al2[2], bh[2], bl2[2];
#pragma unroll
        for (int mt = 0; mt < 2; ++mt) {
            ah[mt] = *(v8bf*)&Th[(mt * 16 + lr) * 264 + k0 + q * 8];
            al2[mt] = *(v8bf*)&Tl[(mt * 16 + lr) * 264 + k0 + q * 8];
        }
#pragma unroll
        for (int nt = 0; nt < 2; ++nt) {
            bh[nt] = *(v8bf*)&Bh[(w * 32 + nt * 16 + lr) * 40 + q * 8];
            bl2[nt] = *(v8bf*)&Bl[(w * 32 + nt * 16 + lr) * 40 + q * 8];
        }
#pragma unroll
        for (int mt = 0; mt < 2; ++mt)
#pragma unroll
            for (int nt = 0; nt < 2; ++nt) {
                v4f a = acc2[mt][nt];
                a = __builtin_amdgcn_mfma_f32_16x16x32_bf16(al2[mt], bh[nt], a, 0, 0, 0);
                a = __builtin_amdgcn_mfma_f32_16x16x32_bf16(ah[mt], bl2[nt], a, 0, 0, 0);
                a = __builtin_amdgcn_mfma_f32_16x16x32_bf16(ah[mt], bh[nt], a, 0, 0, 0);
                acc2[mt][nt] = a;
            }
        __syncthreads();
    }
#pragma unroll
    for (int mt = 0; mt < 2; ++mt)
#pragma unroll
        for (int nt = 0; nt < 2; ++nt)
#pragma unroll
            for (int reg = 0; reg < 4; ++reg) {
                int row = mt * 16 + q * 4 + reg;
                int col = w * 32 + nt * 16 + lr;
                xout[(size_t)(r0 + row) * H + col] = acc2[mt][nt][reg] + gb2[col];
            }
}

// ---------------- readout ----------------

__global__ void k_seg_batch(const float* __restrict__ x, const int* __restrict__ batch,
                            float* __restrict__ xgsum, float* __restrict__ gcnt) {
    int h = threadIdx.x;
    int r0 = blockIdx.x * 256;
    if (r0 >= Nn) return;
    int r1 = min(r0 + 256, Nn);
    int cur = batch[r0];
    float acc = 0.f, c = 0.f;
    for (int r = r0; r < r1; ++r) {
        int b = batch[r];
        if (b != cur) {
            atomicAdd(&xgsum[cur * H + h], acc);
            if (h == 0) atomicAdd(&gcnt[cur], c);
            acc = 0.f;
            c = 0.f;
            cur = b;
        }
        acc += x[r * H + h];
        c += 1.f;
    }
    atomicAdd(&xgsum[cur * H + h], acc);
    if (h == 0) atomicAdd(&gcnt[cur], c);
}

__global__ void k_head(const float* __restrict__ xgsum, const float* __restrict__ gcnt,
                       const float* __restrict__ alw, const float* __restrict__ alb,
                       const float* __restrict__ lw, const float* __restrict__ lb,
                       float* __restrict__ out) {
    __shared__ float mean[H];
    __shared__ float red[H];
    int g = blockIdx.x, j = threadIdx.x;
    mean[j] = xgsum[g * H + j] / fmaxf(gcnt[g], 1.f);
    __syncthreads();
    float acc = alb[j];
    for (int k = 0; k < H; ++k) acc += mean[k] * alw[k * H + j];
    acc = fmaxf(acc, 0.f) * lw[j];
    red[j] = acc;
    __syncthreads();
    for (int s = 64; s > 0; s >>= 1) {
        if (j < s) red[j] += red[j + s];
        __syncthreads();
    }
    if (j == 0) out[g] = red[0] + lb[0];
}

// ---------------- host ----------------

extern "C" void kernel_launch(void* const* d_in, const int* in_sizes, int n_in,
                              void* d_out, int out_size, void* d_ws, size_t ws_size,
                              hipStream_t stream) {
    const int* x_atom = (const int*)d_in[0];
    const int* ei = (const int*)d_in[1];
    const int* eattr = (const int*)d_in[2];
    const int* batch = (const int*)d_in[3];
    const int* xc5 = (const int*)d_in[4];
    const int* xc6 = (const int*)d_in[5];
    const int* a2c5_row = (const int*)d_in[6];
    const int* a2c6_row = (const int*)d_in[8];
    const float* atom_emb = (const float*)d_in[10];
    const float* bond_emb = (const float*)d_in[11];
    const float* cyc5 = (const float*)d_in[12];
    const float* cyc6 = (const float*)d_in[13];
    const float* eps = (const float*)d_in[14];
    const float* gw1 = (const float*)d_in[15];
    const float* gb1 = (const float*)d_in[16];
    const float* gbn_g = (const float*)d_in[17];
    const float* gbn_b = (const float*)d_in[18];
    const float* gw2 = (const float*)d_in[19];
    const float* gb2 = (const float*)d_in[20];
    const float* bn_g = (const float*)d_in[21];
    const float* bn_b = (const float*)d_in[22];
    const float* a2c5_w = (const float*)d_in[23];
    const float* a2c5_b = (const float*)d_in[24];
    const float* a2c6_w = (const float*)d_in[25];
    const float* a2c6_b = (const float*)d_in[26];
    const float* c2a5_w = (const float*)d_in[27];
    const float* c2a5_b = (const float*)d_in[28];
    const float* c2a6_w = (const float*)d_in[29];
    const float* c2a6_b = (const float*)d_in[30];
    const float* p5_w = (const float*)d_in[31];
    const float* p5_b = (const float*)d_in[32];
    const float* p6_w = (const float*)d_in[33];
    const float* p6_b = (const float*)d_in[34];
    const float* alw = (const float*)d_in[35];
    const float* alb = (const float*)d_in[36];
    const float* lw = (const float*)d_in[37];
    const float* lb = (const float*)d_in[38];
    float* out = (float*)d_out;

    float* w = (float*)d_ws;
    size_t o = 0;
    auto alloc = [&](size_t nf) {
        float* p = w + o;
        o += (nf + 63) & ~(size_t)63;
        return p;
    };
    float* x = alloc((size_t)Nn * H);
    float* x5 = alloc((size_t)N5c * 5 * H);
    float* x6 = alloc((size_t)N6c * 6 * H);
    float* agg = alloc((size_t)Nn * H);
    float* cnt = alloc(Nn);
    float* stats = alloc(512);
    float* xgsum = alloc((size_t)Gg * H);
    float* gcnt = alloc(Gg);

    const int TPB = 256;
    auto cdiv = [](int a, int b) { return (a + b - 1) / b; };

    k_atom_enc<<<cdiv(Nn * H, TPB), TPB, 0, stream>>>(x_atom, atom_emb, x);
    k_cyc_init<<<cdiv(N5c * 5 * H, TPB), TPB, 0, stream>>>(xc5, cyc5, x5, N5c * 5);
    k_cyc_init<<<cdiv(N6c * 6 * H, TPB), TPB, 0, stream>>>(xc6, cyc6, x6, N6c * 6);

    for (int i = 0; i < Ll; ++i) {
        // GINE aggregation -> agg (= hin)
        hipMemsetAsync(agg, 0, (size_t)Nn * H * 4, stream);
        k_edge_scatter<<<cdiv(Ee * H, TPB), TPB, 0, stream>>>(
            x, ei, eattr, bond_emb + (size_t)i * BF * BV * H, agg);
        k_hin<<<cdiv(Nn * H, TPB), TPB, 0, stream>>>(x, eps, agg, i);

        // BN1 stats (h1 never materialized)
        hipMemsetAsync(stats, 0, 512 * 4, stream);
        dim3 gst(cdiv(Nn, 128), 2);
        k_mgemm<<<gst, 256, 0, stream>>>(agg, gw1 + (size_t)i * H * 2 * H,
                                         gb1 + (size_t)i * 2 * H, nullptr, nullptr,
                                         nullptr, stats, Nn, 128, 256, 0, 0, 0, 1);
        // fused MLP -> x (pre-BN2)
        k_mlp_mfma<<<Nn / 32, 256, 0, stream>>>(
            agg, gw1 + (size_t)i * H * 2 * H, gb1 + (size_t)i * 2 * H,
            gbn_g + (size_t)i * 2 * H, gbn_b + (size_t)i * 2 * H,
            gw2 + (size_t)i * 2 * H * H, gb2 + (size_t)i * H, stats, x);

        // BN2 + relu on x
        hipMemsetAsync(stats, 0, 512 * 4, stream);
        k_bn_stats<<<cdiv(Nn, 64), H, 0, stream>>>(x, stats, Nn, H, 64);
        k_bn_apply<<<cdiv(Nn * H, TPB), TPB, 0, stream>>>(
            x, stats, bn_g + (size_t)i * H, bn_b + (size_t)i * H, Nn, H);

        // atoms -> cycles (gather GEMM, in-place residual)
        dim3 g5(cdiv(N5c * 5, 128), 1);
        k_mgemm<<<g5, 256, 0, stream>>>(x, a2c5_w + (size_t)i * H * H,
                                        a2c5_b + (size_t)i * H, x5, x5, a2c5_row,
                                        nullptr, N5c * 5, 128, 128, 0, 1, 0, 0);
        dim3 g6(cdiv(N6c * 6, 128), 1);
        k_mgemm<<<g6, 256, 0, stream>>>(x, a2c6_w + (size_t)i * H * H,
                                        a2c6_b + (size_t)i * H, x6, x6, a2c6_row,
                                        nullptr, N6c * 6, 128, 128, 0, 1, 0, 0);

        // cyclic path blocks -> agg (tmp), copy back; x6 in 2 chunks
        k_mgemm<<<g5, 256, 0, stream>>>(x5, p5_w + (size_t)i * 3 * H * H,
                                        p5_b + (size_t)i * H, x5, agg, nullptr,
                                        nullptr, N5c * 5, 384, 128, 5, 1, 0, 0);
        hipMemcpyAsync(x5, agg, (size_t)N5c * 5 * H * 4, hipMemcpyDeviceToDevice, stream);
        const int C6 = (N6c / 2) * 6;  // 90000 rows per chunk
        for (int ch = 0; ch < 2; ++ch) {
            dim3 gc(cdiv(C6, 128), 1);
            k_mgemm<<<gc, 256, 0, stream>>>(x6, p6_w + (size_t)i * 3 * H * H,
                                            p6_b + (size_t)i * H, x6, agg, nullptr,
                                            nullptr, C6, 384, 128, 6, 1, ch * C6, 0);
            hipMemcpyAsync(x6 + (size_t)ch * C6 * H, agg, (size_t)C6 * H * 4,
                           hipMemcpyDeviceToDevice, stream);
        }

        // cycles -> atoms (scatter-mean -> agg, GEMM residual into x)
        dim3 ga(cdiv(Nn, 128), 1);
        hipMemsetAsync(agg, 0, (size_t)Nn * H * 4, stream);
        hipMemsetAsync(cnt, 0, (size_t)Nn * 4, stream);
        k_scatter_add<<<cdiv(N5c * 5 * H, TPB), TPB, 0, stream>>>(x5, a2c5_row, agg, cnt, N5c * 5);
        k_div_cnt<<<cdiv(Nn * H, TPB), TPB, 0, stream>>>(agg, cnt);
        k_mgemm<<<ga, 256, 0, stream>>>(agg, c2a5_w + (size_t)i * H * H,
                                        c2a5_b + (size_t)i * H, x, x, nullptr,
                                        nullptr, Nn, 128, 128, 0, 1, 0, 0);
        hipMemsetAsync(agg, 0, (size_t)Nn * H * 4, stream);
        hipMemsetAsync(cnt, 0, (size_t)Nn * 4, stream);
        k_scatter_add<<<cdiv(N6c * 6 * H, TPB), TPB, 0, stream>>>(x6, a2c6_row, agg, cnt, N6c * 6);
        k_div_cnt<<<cdiv(Nn * H, TPB), TPB, 0, stream>>>(agg, cnt);
        k_mgemm<<<ga, 256, 0, stream>>>(agg, c2a6_w + (size_t)i * H * H,
                                        c2a6_b + (size_t)i * H, x, x, nullptr,
                                        nullptr, Nn, 128, 128, 0, 1, 0, 0);
    }

    // readout
    hipMemsetAsync(xgsum, 0, (size_t)Gg * H * 4, stream);
    hipMemsetAsync(gcnt, 0, (size_t)Gg * 4, stream);
    k_seg_batch<<<cdiv(Nn, 256), H, 0, stream>>>(x, batch, xgsum, gcnt);
    k_head<<<Gg, H, 0, stream>>>(xgsum, gcnt, alw, alb, lw, lb, out);
}